// Round 1
// baseline (240.887 us; speedup 1.0000x reference)
//
#include <hip/hip_runtime.h>
#include <hip/hip_bf16.h>

typedef short bf16x8 __attribute__((ext_vector_type(8)));
typedef short bf16x4 __attribute__((ext_vector_type(4)));
typedef float f32x4 __attribute__((ext_vector_type(4)));

#define D_DIM 64
#define QBLK 64
#define KVBLK 64

// float -> bf16 (round-to-nearest-even), bit pattern as ushort
__device__ __forceinline__ unsigned short f2bf(float f) {
    unsigned u = __builtin_bit_cast(unsigned, f);
    u += 0x7fffu + ((u >> 16) & 1u);
    return (unsigned short)(u >> 16);
}

// LDS byte address for row-major [R][64] bf16 tile (row stride 128B),
// XOR-swizzled to break the 128B-stride same-bank pattern (T2).
// Involution: same formula on write and read.
__device__ __forceinline__ unsigned swz(unsigned row, unsigned colByte) {
    return (row * 128u + colByte) ^ ((row & 7u) << 4);
}

__global__ __launch_bounds__(256) void attn_fwd_kernel(
    const float* __restrict__ Qp, const float* __restrict__ Kp,
    const float* __restrict__ Vp, float* __restrict__ Op, int S)
{
    __shared__ __align__(16) unsigned char lds_k[KVBLK * 128];    // K tile bf16 [kv=64][d=64]
    __shared__ __align__(16) unsigned char lds_vt[D_DIM * 128];   // V^T tile bf16 [d=64][kv=64]
    __shared__ __align__(16) unsigned char lds_p[4 * 16 * 128];   // per-wave P bf16 [q=16][kv=64]

    const int qt   = blockIdx.x;
    const int bh   = blockIdx.y;
    const int tid  = threadIdx.x;
    const int w    = tid >> 6;    // wave 0..3
    const int lane = tid & 63;
    const int lo   = lane & 15;   // lane%16
    const int hi   = lane >> 4;   // lane/16, 0..3

    const long base = (long)bh * S * D_DIM;
    const float* qp = Qp + base;
    const float* kp = Kp + base;
    const float* vp = Vp + base;
    float*       op = Op + base;

    const int q0 = qt * QBLK;
    const int qw = q0 + w * 16;   // this wave's first q row

    // ---- Q fragments (held in registers for the whole kernel), scaled by 1/sqrt(D) ----
    // A-frag layout: row = lane&15, k = f*32 + hi*8 + i (8 contiguous bf16 per lane)
    bf16x8 qf[2];
    {
        const float* src = qp + (long)(qw + lo) * D_DIM + hi * 8;
        #pragma unroll
        for (int f = 0; f < 2; ++f) {
            float4 a = *(const float4*)(src + f * 32);
            float4 b = *(const float4*)(src + f * 32 + 4);
            bf16x8 v;
            v[0] = (short)f2bf(a.x * 0.125f);
            v[1] = (short)f2bf(a.y * 0.125f);
            v[2] = (short)f2bf(a.z * 0.125f);
            v[3] = (short)f2bf(a.w * 0.125f);
            v[4] = (short)f2bf(b.x * 0.125f);
            v[5] = (short)f2bf(b.y * 0.125f);
            v[6] = (short)f2bf(b.z * 0.125f);
            v[7] = (short)f2bf(b.w * 0.125f);
            qf[f] = v;
        }
    }

    // online-softmax state; o_acc[dt] holds O[q=(hi*4+reg)][d=dt*16+lo]
    f32x4 o_acc[4];
    float m_r[4], l_r[4];
    #pragma unroll
    for (int r = 0; r < 4; ++r) { m_r[r] = -__builtin_inff(); l_r[r] = 0.f; }
    #pragma unroll
    for (int dt = 0; dt < 4; ++dt) o_acc[dt] = (f32x4){0.f, 0.f, 0.f, 0.f};

    const unsigned pbase = (unsigned)w * (16 * 128);

    for (int t = 0; t <= qt; ++t) {
        const long kv0 = (long)t * KVBLK;

        __syncthreads();   // previous iteration's LDS reads done before overwrite
        // ---- cooperative stage: K -> lds_k (row-major), V -> lds_vt (transposed) ----
        #pragma unroll
        for (int j = 0; j < 4; ++j) {
            int n = tid + 256 * j;        // float4 index 0..1023
            int r = n >> 4;               // kv row 0..63
            int c = (n & 15) << 2;        // d col 0,4,...,60
            float4 kk = *(const float4*)(kp + (kv0 + r) * D_DIM + c);
            bf16x4 kb;
            kb[0] = (short)f2bf(kk.x); kb[1] = (short)f2bf(kk.y);
            kb[2] = (short)f2bf(kk.z); kb[3] = (short)f2bf(kk.w);
            *(bf16x4*)&lds_k[swz((unsigned)r, (unsigned)c * 2)] = kb;

            float4 vv = *(const float4*)(vp + (kv0 + r) * D_DIM + c);
            *(unsigned short*)&lds_vt[swz((unsigned)(c + 0), (unsigned)r * 2)] = f2bf(vv.x);
            *(unsigned short*)&lds_vt[swz((unsigned)(c + 1), (unsigned)r * 2)] = f2bf(vv.y);
            *(unsigned short*)&lds_vt[swz((unsigned)(c + 2), (unsigned)r * 2)] = f2bf(vv.z);
            *(unsigned short*)&lds_vt[swz((unsigned)(c + 3), (unsigned)r * 2)] = f2bf(vv.w);
        }
        __syncthreads();

        // ---- scores: S = Q K^T (per wave: 16q x 64kv), C layout row=q, col=kv ----
        float sc[4][4];   // [kc][reg]
        #pragma unroll
        for (int kc = 0; kc < 4; ++kc) {
            f32x4 s = (f32x4){0.f, 0.f, 0.f, 0.f};
            #pragma unroll
            for (int f = 0; f < 2; ++f) {
                bf16x8 kf = *(const bf16x8*)&lds_k[swz((unsigned)(kc * 16 + lo),
                                                       (unsigned)(hi * 16 + f * 64))];
                s = __builtin_amdgcn_mfma_f32_16x16x32_bf16(qf[f], kf, s, 0, 0, 0);
            }
            #pragma unroll
            for (int r = 0; r < 4; ++r) sc[kc][r] = s[r];
        }

        // ---- causal mask (diagonal block only; q0 == kv0 there) ----
        if (t == qt) {
            #pragma unroll
            for (int kc = 0; kc < 4; ++kc) {
                #pragma unroll
                for (int r = 0; r < 4; ++r) {
                    int qg = w * 16 + hi * 4 + r;
                    int kg = kc * 16 + lo;
                    if (kg > qg) sc[kc][r] = -__builtin_inff();
                }
            }
        }

        // ---- online softmax (row = 16 lanes sharing lane>>4 group) ----
        float scale[4];
        #pragma unroll
        for (int r = 0; r < 4; ++r) {
            float mx = fmaxf(fmaxf(sc[0][r], sc[1][r]), fmaxf(sc[2][r], sc[3][r]));
            mx = fmaxf(mx, __shfl_xor(mx, 1));
            mx = fmaxf(mx, __shfl_xor(mx, 2));
            mx = fmaxf(mx, __shfl_xor(mx, 4));
            mx = fmaxf(mx, __shfl_xor(mx, 8));
            float mn = fmaxf(m_r[r], mx);
            scale[r] = __expf(m_r[r] - mn);
            m_r[r] = mn;
            float s0 = 0.f;
            #pragma unroll
            for (int kc = 0; kc < 4; ++kc) {
                float p = __expf(sc[kc][r] - mn);
                sc[kc][r] = p;
                s0 += p;
            }
            s0 += __shfl_xor(s0, 1);
            s0 += __shfl_xor(s0, 2);
            s0 += __shfl_xor(s0, 4);
            s0 += __shfl_xor(s0, 8);
            l_r[r] = l_r[r] * scale[r] + s0;
        }

        // ---- write P (bf16) to this wave's private LDS tile; rescale O ----
        #pragma unroll
        for (int r = 0; r < 4; ++r) {
            unsigned qr = (unsigned)(hi * 4 + r);
            #pragma unroll
            for (int kc = 0; kc < 4; ++kc)
                *(unsigned short*)&lds_p[pbase + swz(qr, (unsigned)((kc * 16 + lo) * 2))] =
                    f2bf(sc[kc][r]);
            #pragma unroll
            for (int dt = 0; dt < 4; ++dt) o_acc[dt][r] *= scale[r];
        }

        // ---- PV: O += P V  (A = P frags, B = V^T frags; same k-map both sides) ----
        bf16x8 pa0 = *(const bf16x8*)&lds_p[pbase + swz((unsigned)lo, (unsigned)(hi * 16))];
        bf16x8 pa1 = *(const bf16x8*)&lds_p[pbase + swz((unsigned)lo, (unsigned)(hi * 16 + 64))];
        #pragma unroll
        for (int dt = 0; dt < 4; ++dt) {
            bf16x8 vb0 = *(const bf16x8*)&lds_vt[swz((unsigned)(dt * 16 + lo),
                                                     (unsigned)(hi * 16))];
            bf16x8 vb1 = *(const bf16x8*)&lds_vt[swz((unsigned)(dt * 16 + lo),
                                                     (unsigned)(hi * 16 + 64))];
            o_acc[dt] = __builtin_amdgcn_mfma_f32_16x16x32_bf16(pa0, vb0, o_acc[dt], 0, 0, 0);
            o_acc[dt] = __builtin_amdgcn_mfma_f32_16x16x32_bf16(pa1, vb1, o_acc[dt], 0, 0, 0);
        }
    }

    // ---- epilogue: O = acc / l ----
    const int qrow = qw + hi * 4;
    #pragma unroll
    for (int r = 0; r < 4; ++r) {
        float inv = 1.f / l_r[r];
        #pragma unroll
        for (int dt = 0; dt < 4; ++dt)
            op[(long)(qrow + r) * D_DIM + dt * 16 + lo] = o_acc[dt][r] * inv;
    }
}

extern "C" void kernel_launch(void* const* d_in, const int* in_sizes, int n_in,
                              void* d_out, int out_size, void* d_ws, size_t ws_size,
                              hipStream_t stream) {
    const float* q = (const float*)d_in[0];
    const float* k = (const float*)d_in[1];
    const float* v = (const float*)d_in[2];
    float* o = (float*)d_out;

    const int S = 2048;
    const int BH = in_sizes[0] / (S * D_DIM);   // = B*H = 32

    dim3 grid(S / QBLK, BH);
    attn_fwd_kernel<<<grid, 256, 0, stream>>>(q, k, v, o, S);
}

// Round 2
// 90.027 us; speedup vs baseline: 2.6757x; 2.6757x over previous
//
#include <hip/hip_runtime.h>
#include <hip/hip_bf16.h>

typedef short bf16x8 __attribute__((ext_vector_type(8)));
typedef short bf16x4 __attribute__((ext_vector_type(4)));
typedef float f32x4 __attribute__((ext_vector_type(4)));

#define D_DIM 64
#define SEQ 2048
#define NTILE 32          // 2048/64 kv (and q) tiles
#define BHD (SEQ * D_DIM) // per-bh elements = 131072

// float -> bf16 (round-to-nearest-even)
__device__ __forceinline__ unsigned short f2bf(float f) {
    unsigned u = __builtin_bit_cast(unsigned, f);
    u += 0x7fffu + ((u >> 16) & 1u);
    return (unsigned short)(u >> 16);
}

// XOR-swizzled byte address for row-major [R][64] bf16 tile (row stride 128B) — T2
__device__ __forceinline__ unsigned swz(unsigned row, unsigned colByte) {
    return (row * 128u + colByte) ^ ((row & 7u) << 4);
}

__device__ __forceinline__ void gl_lds(const unsigned short* g, unsigned char* lds_generic,
                                       unsigned lds_off) {
    __builtin_amdgcn_global_load_lds(
        (const __attribute__((address_space(1))) void*)g,
        (__attribute__((address_space(3))) void*)(lds_generic + lds_off), 16, 0, 0);
}

// ---------------- prepass 1: fp32 -> bf16 elementwise (for K) ----------------
__global__ __launch_bounds__(256) void conv_bf16_kernel(const float* __restrict__ in,
                                                        unsigned short* __restrict__ out,
                                                        int n8) {
    int idx = blockIdx.x * 256 + threadIdx.x;
    for (int i = idx; i < n8; i += gridDim.x * 256) {
        const float* p = in + (size_t)i * 8;
        float4 a = *(const float4*)p;
        float4 b = *(const float4*)(p + 4);
        bf16x8 v;
        v[0] = (short)f2bf(a.x); v[1] = (short)f2bf(a.y);
        v[2] = (short)f2bf(a.z); v[3] = (short)f2bf(a.w);
        v[4] = (short)f2bf(b.x); v[5] = (short)f2bf(b.y);
        v[6] = (short)f2bf(b.z); v[7] = (short)f2bf(b.w);
        *(bf16x8*)(out + (size_t)i * 8) = v;
    }
}

// ---------------- prepass 2: V [bh][s][d] fp32 -> Vt [bh][d][s] bf16 ----------------
__global__ __launch_bounds__(256) void vt_kernel(const float* __restrict__ V,
                                                 unsigned short* __restrict__ Vt) {
    __shared__ unsigned short t[64][66];   // +2 pad: column reads spread banks
    const int st = blockIdx.x;             // s-tile 0..31
    const int bh = blockIdx.y;
    const int tid = threadIdx.x;
    const float* vb = V + (size_t)bh * BHD + st * 64 * D_DIM;

    #pragma unroll
    for (int j = 0; j < 4; ++j) {
        int n = tid + 256 * j;         // float4 index
        int r = n >> 4;                // s row in tile
        int c = (n & 15) << 2;         // d col
        float4 v = *(const float4*)(vb + r * D_DIM + c);
        t[r][c + 0] = f2bf(v.x); t[r][c + 1] = f2bf(v.y);
        t[r][c + 2] = f2bf(v.z); t[r][c + 3] = f2bf(v.w);
    }
    __syncthreads();
    #pragma unroll
    for (int j = 0; j < 2; ++j) {
        int m = tid + 256 * j;
        int d = m >> 3;                // d row 0..63
        int s8 = (m & 7) << 3;         // s chunk
        bf16x8 o;
        #pragma unroll
        for (int e = 0; e < 8; ++e) o[e] = (short)t[s8 + e][d];
        *(bf16x8*)(Vt + (size_t)bh * BHD + (size_t)d * SEQ + st * 64 + s8) = o;
    }
}

// ---------------- main attention kernel (bf16 K / V^T from ws) ----------------
__global__ __launch_bounds__(256) void attn_fwd(const float* __restrict__ Qp,
                                                const unsigned short* __restrict__ Kb,
                                                const unsigned short* __restrict__ Vtb,
                                                float* __restrict__ Op) {
    // LDS: 3 buffers x (K 8KB | Vt 8KB) + 4 waves x 2KB P = 57344 B
    __shared__ __align__(16) unsigned char lds[57344];

    // linear block id, XCD-aware swizzle (512 = 8 XCDs x 64, bijective)
    int id = blockIdx.y * gridDim.x + blockIdx.x;
    int wid = (id & 7) * 64 + (id >> 3);
    const int i  = wid & 15;     // pair index: q-tiles i and 31-i (constant work)
    const int bh = wid >> 4;

    const int tid = threadIdx.x;
    const int w    = tid >> 6;
    const int lane = tid & 63;
    const int lo   = lane & 15;
    const int hi   = lane >> 4;

    const size_t base = (size_t)bh * BHD;
    const float* qp = Qp + base;
    const unsigned short* kb = Kb + base;
    const unsigned short* vt = Vtb + base;
    float* op = Op + base;

    // staging geometry: linear LDS slot -> (row, swizzled colByte) -> global element
    int kOff[2], vOff[2];
    unsigned ldsOff[2];
    #pragma unroll
    for (int p = 0; p < 2; ++p) {
        int L = p * 4096 + w * 1024 + lane * 16;
        int row = L >> 7;
        int cb = (L & 127) ^ ((row & 7) << 4);
        kOff[p] = row * D_DIM + (cb >> 1);
        vOff[p] = row * SEQ + (cb >> 1);
        ldsOff[p] = (unsigned)(p * 4096 + w * 1024);
    }
    const unsigned pbase = 49152u + (unsigned)w * 2048u;

    auto STAGE = [&](int b, int t) {
        const unsigned short* kg = kb + t * (64 * D_DIM);
        const unsigned short* vg = vt + t * 64;
        unsigned bb = (unsigned)b * 16384u;
        #pragma unroll
        for (int p = 0; p < 2; ++p) {
            gl_lds(kg + kOff[p], lds, bb + ldsOff[p]);
            gl_lds(vg + vOff[p], lds, bb + 8192u + ldsOff[p]);
        }
    };

    #pragma unroll 1
    for (int ph = 0; ph < 2; ++ph) {
        const int qt = ph ? (NTILE - 1 - i) : i;
        const int nt = qt + 1;
        const int qw = qt * 64 + w * 16;

        __builtin_amdgcn_s_barrier();          // prev phase readers done before restage
        __builtin_amdgcn_sched_barrier(0);
        STAGE(0, 0);
        if (nt > 1) STAGE(1, 1);

        // Q fragments (fp32 load, scaled, bf16) — once per phase
        bf16x8 qf[2];
        {
            const float* src = qp + (size_t)(qw + lo) * D_DIM + hi * 8;
            #pragma unroll
            for (int f = 0; f < 2; ++f) {
                float4 a = *(const float4*)(src + f * 32);
                float4 b = *(const float4*)(src + f * 32 + 4);
                bf16x8 v;
                v[0] = (short)f2bf(a.x * 0.125f); v[1] = (short)f2bf(a.y * 0.125f);
                v[2] = (short)f2bf(a.z * 0.125f); v[3] = (short)f2bf(a.w * 0.125f);
                v[4] = (short)f2bf(b.x * 0.125f); v[5] = (short)f2bf(b.y * 0.125f);
                v[6] = (short)f2bf(b.z * 0.125f); v[7] = (short)f2bf(b.w * 0.125f);
                qf[f] = v;
            }
        }

        f32x4 o_acc[4];
        float m_r[4], l_r[4];
        #pragma unroll
        for (int r = 0; r < 4; ++r) { m_r[r] = -__builtin_inff(); l_r[r] = 0.f; }
        #pragma unroll
        for (int dt = 0; dt < 4; ++dt) o_acc[dt] = (f32x4){0.f, 0.f, 0.f, 0.f};

        #pragma unroll 1
        for (int t = 0; t < nt; ++t) {
            // wait current tile's loads (older than the one prefetch in flight)
            if (t < nt - 1) asm volatile("s_waitcnt vmcnt(4)" ::: "memory");
            else            asm volatile("s_waitcnt vmcnt(0)" ::: "memory");
            __builtin_amdgcn_s_barrier();
            __builtin_amdgcn_sched_barrier(0);
            if (t + 2 < nt) STAGE((t + 2) % 3, t + 2);

            const unsigned kbuf = (unsigned)(t % 3) * 16384u;
            const unsigned vbuf = kbuf + 8192u;

            // ---- QK^T ----
            float sc[4][4];
            #pragma unroll
            for (int kc = 0; kc < 4; ++kc) {
                f32x4 s = (f32x4){0.f, 0.f, 0.f, 0.f};
                #pragma unroll
                for (int f = 0; f < 2; ++f) {
                    bf16x8 kf = *(const bf16x8*)&lds[kbuf +
                        swz((unsigned)(kc * 16 + lo), (unsigned)(hi * 16 + f * 64))];
                    s = __builtin_amdgcn_mfma_f32_16x16x32_bf16(qf[f], kf, s, 0, 0, 0);
                }
                #pragma unroll
                for (int r = 0; r < 4; ++r) sc[kc][r] = s[r];
            }

            // ---- causal mask (diagonal tile) ----
            if (t == qt) {
                #pragma unroll
                for (int kc = 0; kc < 4; ++kc) {
                    #pragma unroll
                    for (int r = 0; r < 4; ++r) {
                        int qg = w * 16 + hi * 4 + r;
                        int kg = kc * 16 + lo;
                        if (kg > qg) sc[kc][r] = -__builtin_inff();
                    }
                }
            }

            // ---- online softmax (16-lane row groups) ----
            float scale[4];
            #pragma unroll
            for (int r = 0; r < 4; ++r) {
                float mx = fmaxf(fmaxf(sc[0][r], sc[1][r]), fmaxf(sc[2][r], sc[3][r]));
                mx = fmaxf(mx, __shfl_xor(mx, 1));
                mx = fmaxf(mx, __shfl_xor(mx, 2));
                mx = fmaxf(mx, __shfl_xor(mx, 4));
                mx = fmaxf(mx, __shfl_xor(mx, 8));
                float mn = fmaxf(m_r[r], mx);
                scale[r] = __expf(m_r[r] - mn);
                m_r[r] = mn;
                float s0 = 0.f;
                #pragma unroll
                for (int kc = 0; kc < 4; ++kc) {
                    float p = __expf(sc[kc][r] - mn);
                    sc[kc][r] = p;
                    s0 += p;
                }
                s0 += __shfl_xor(s0, 1);
                s0 += __shfl_xor(s0, 2);
                s0 += __shfl_xor(s0, 4);
                s0 += __shfl_xor(s0, 8);
                l_r[r] = l_r[r] * scale[r] + s0;
            }

            // ---- P -> per-wave LDS tile (bf16); rescale O ----
            #pragma unroll
            for (int r = 0; r < 4; ++r) {
                unsigned qr = (unsigned)(hi * 4 + r);
                #pragma unroll
                for (int kc = 0; kc < 4; ++kc)
                    *(unsigned short*)&lds[pbase + swz(qr, (unsigned)((kc * 16 + lo) * 2))] =
                        f2bf(sc[kc][r]);
                #pragma unroll
                for (int dt = 0; dt < 4; ++dt) o_acc[dt][r] *= scale[r];
            }

            // ---- PV ----
            bf16x8 pa0 = *(const bf16x8*)&lds[pbase + swz((unsigned)lo, (unsigned)(hi * 16))];
            bf16x8 pa1 = *(const bf16x8*)&lds[pbase + swz((unsigned)lo, (unsigned)(hi * 16 + 64))];
            #pragma unroll
            for (int dt = 0; dt < 4; ++dt) {
                bf16x8 vb0 = *(const bf16x8*)&lds[vbuf +
                    swz((unsigned)(dt * 16 + lo), (unsigned)(hi * 16))];
                bf16x8 vb1 = *(const bf16x8*)&lds[vbuf +
                    swz((unsigned)(dt * 16 + lo), (unsigned)(hi * 16 + 64))];
                o_acc[dt] = __builtin_amdgcn_mfma_f32_16x16x32_bf16(pa0, vb0, o_acc[dt], 0, 0, 0);
                o_acc[dt] = __builtin_amdgcn_mfma_f32_16x16x32_bf16(pa1, vb1, o_acc[dt], 0, 0, 0);
            }
        }

        // ---- epilogue ----
        const int qrow = qw + hi * 4;
        #pragma unroll
        for (int r = 0; r < 4; ++r) {
            float inv = 1.f / l_r[r];
            #pragma unroll
            for (int dt = 0; dt < 4; ++dt)
                op[(size_t)(qrow + r) * D_DIM + dt * 16 + lo] = o_acc[dt][r] * inv;
        }
    }
}

// ---------------- fallback (round-1 proven kernel) if ws too small ----------------
__global__ __launch_bounds__(256) void attn_fwd_fb(
    const float* __restrict__ Qp, const float* __restrict__ Kp,
    const float* __restrict__ Vp, float* __restrict__ Op, int S)
{
    __shared__ __align__(16) unsigned char lds_k[64 * 128];
    __shared__ __align__(16) unsigned char lds_vt[64 * 128];
    __shared__ __align__(16) unsigned char lds_p[4 * 16 * 128];

    const int qt = blockIdx.x, bh = blockIdx.y, tid = threadIdx.x;
    const int w = tid >> 6, lane = tid & 63, lo = lane & 15, hi = lane >> 4;
    const size_t base = (size_t)bh * S * D_DIM;
    const float* qp = Qp + base; const float* kp = Kp + base;
    const float* vp = Vp + base; float* op = Op + base;
    const int qw = qt * 64 + w * 16;

    bf16x8 qf[2];
    {
        const float* src = qp + (size_t)(qw + lo) * D_DIM + hi * 8;
        #pragma unroll
        for (int f = 0; f < 2; ++f) {
            float4 a = *(const float4*)(src + f * 32);
            float4 b = *(const float4*)(src + f * 32 + 4);
            bf16x8 v;
            v[0] = (short)f2bf(a.x * 0.125f); v[1] = (short)f2bf(a.y * 0.125f);
            v[2] = (short)f2bf(a.z * 0.125f); v[3] = (short)f2bf(a.w * 0.125f);
            v[4] = (short)f2bf(b.x * 0.125f); v[5] = (short)f2bf(b.y * 0.125f);
            v[6] = (short)f2bf(b.z * 0.125f); v[7] = (short)f2bf(b.w * 0.125f);
            qf[f] = v;
        }
    }
    f32x4 o_acc[4]; float m_r[4], l_r[4];
    #pragma unroll
    for (int r = 0; r < 4; ++r) { m_r[r] = -__builtin_inff(); l_r[r] = 0.f; }
    #pragma unroll
    for (int dt = 0; dt < 4; ++dt) o_acc[dt] = (f32x4){0.f, 0.f, 0.f, 0.f};
    const unsigned pbase = (unsigned)w * 2048u;

    for (int t = 0; t <= qt; ++t) {
        const size_t kv0 = (size_t)t * 64;
        __syncthreads();
        #pragma unroll
        for (int j = 0; j < 4; ++j) {
            int n = tid + 256 * j;
            int r = n >> 4, c = (n & 15) << 2;
            float4 kk = *(const float4*)(kp + (kv0 + r) * D_DIM + c);
            bf16x4 kbv;
            kbv[0] = (short)f2bf(kk.x); kbv[1] = (short)f2bf(kk.y);
            kbv[2] = (short)f2bf(kk.z); kbv[3] = (short)f2bf(kk.w);
            *(bf16x4*)&lds_k[swz((unsigned)r, (unsigned)c * 2)] = kbv;
            float4 vv = *(const float4*)(vp + (kv0 + r) * D_DIM + c);
            *(unsigned short*)&lds_vt[swz((unsigned)(c + 0), (unsigned)r * 2)] = f2bf(vv.x);
            *(unsigned short*)&lds_vt[swz((unsigned)(c + 1), (unsigned)r * 2)] = f2bf(vv.y);
            *(unsigned short*)&lds_vt[swz((unsigned)(c + 2), (unsigned)r * 2)] = f2bf(vv.z);
            *(unsigned short*)&lds_vt[swz((unsigned)(c + 3), (unsigned)r * 2)] = f2bf(vv.w);
        }
        __syncthreads();

        float sc[4][4];
        #pragma unroll
        for (int kc = 0; kc < 4; ++kc) {
            f32x4 s = (f32x4){0.f, 0.f, 0.f, 0.f};
            #pragma unroll
            for (int f = 0; f < 2; ++f) {
                bf16x8 kf = *(const bf16x8*)&lds_k[swz((unsigned)(kc * 16 + lo),
                                                       (unsigned)(hi * 16 + f * 64))];
                s = __builtin_amdgcn_mfma_f32_16x16x32_bf16(qf[f], kf, s, 0, 0, 0);
            }
            #pragma unroll
            for (int r = 0; r < 4; ++r) sc[kc][r] = s[r];
        }
        if (t == qt) {
            #pragma unroll
            for (int kc = 0; kc < 4; ++kc)
                #pragma unroll
                for (int r = 0; r < 4; ++r) {
                    int qg = w * 16 + hi * 4 + r, kg = kc * 16 + lo;
                    if (kg > qg) sc[kc][r] = -__builtin_inff();
                }
        }
        float scale[4];
        #pragma unroll
        for (int r = 0; r < 4; ++r) {
            float mx = fmaxf(fmaxf(sc[0][r], sc[1][r]), fmaxf(sc[2][r], sc[3][r]));
            mx = fmaxf(mx, __shfl_xor(mx, 1)); mx = fmaxf(mx, __shfl_xor(mx, 2));
            mx = fmaxf(mx, __shfl_xor(mx, 4)); mx = fmaxf(mx, __shfl_xor(mx, 8));
            float mn = fmaxf(m_r[r], mx);
            scale[r] = __expf(m_r[r] - mn); m_r[r] = mn;
            float s0 = 0.f;
            #pragma unroll
            for (int kc = 0; kc < 4; ++kc) {
                float p = __expf(sc[kc][r] - mn); sc[kc][r] = p; s0 += p;
            }
            s0 += __shfl_xor(s0, 1); s0 += __shfl_xor(s0, 2);
            s0 += __shfl_xor(s0, 4); s0 += __shfl_xor(s0, 8);
            l_r[r] = l_r[r] * scale[r] + s0;
        }
        #pragma unroll
        for (int r = 0; r < 4; ++r) {
            unsigned qr = (unsigned)(hi * 4 + r);
            #pragma unroll
            for (int kc = 0; kc < 4; ++kc)
                *(unsigned short*)&lds_p[pbase + swz(qr, (unsigned)((kc * 16 + lo) * 2))] =
                    f2bf(sc[kc][r]);
            #pragma unroll
            for (int dt = 0; dt < 4; ++dt) o_acc[dt][r] *= scale[r];
        }
        bf16x8 pa0 = *(const bf16x8*)&lds_p[pbase + swz((unsigned)lo, (unsigned)(hi * 16))];
        bf16x8 pa1 = *(const bf16x8*)&lds_p[pbase + swz((unsigned)lo, (unsigned)(hi * 16 + 64))];
        #pragma unroll
        for (int dt = 0; dt < 4; ++dt) {
            bf16x8 vb0 = *(const bf16x8*)&lds_vt[swz((unsigned)(dt * 16 + lo), (unsigned)(hi * 16))];
            bf16x8 vb1 = *(const bf16x8*)&lds_vt[swz((unsigned)(dt * 16 + lo), (unsigned)(hi * 16 + 64))];
            o_acc[dt] = __builtin_amdgcn_mfma_f32_16x16x32_bf16(pa0, vb0, o_acc[dt], 0, 0, 0);
            o_acc[dt] = __builtin_amdgcn_mfma_f32_16x16x32_bf16(pa1, vb1, o_acc[dt], 0, 0, 0);
        }
    }
    const int qrow = qw + hi * 4;
    #pragma unroll
    for (int r = 0; r < 4; ++r) {
        float inv = 1.f / l_r[r];
        #pragma unroll
        for (int dt = 0; dt < 4; ++dt)
            op[(size_t)(qrow + r) * D_DIM + dt * 16 + lo] = o_acc[dt][r] * inv;
    }
}

extern "C" void kernel_launch(void* const* d_in, const int* in_sizes, int n_in,
                              void* d_out, int out_size, void* d_ws, size_t ws_size,
                              hipStream_t stream) {
    const float* q = (const float*)d_in[0];
    const float* k = (const float*)d_in[1];
    const float* v = (const float*)d_in[2];
    float* o = (float*)d_out;

    const size_t nelem = (size_t)32 * BHD;          // 4,194,304 per tensor
    const size_t need = 2 * nelem * sizeof(unsigned short);  // 16 MiB

    if (ws_size >= need) {
        unsigned short* kbf = (unsigned short*)d_ws;
        unsigned short* vtb = kbf + nelem;
        conv_bf16_kernel<<<2048, 256, 0, stream>>>(k, kbf, (int)(nelem / 8));
        vt_kernel<<<dim3(32, 32), 256, 0, stream>>>(v, vtb);
        attn_fwd<<<dim3(16, 32), 256, 0, stream>>>(q, kbf, vtb, o);
    } else {
        attn_fwd_fb<<<dim3(32, 32), 256, 0, stream>>>(q, k, v, o, SEQ);
    }
}

// Round 3
// 64.397 us; speedup vs baseline: 3.7406x; 1.3980x over previous
//
#include <hip/hip_runtime.h>
#include <hip/hip_bf16.h>

typedef short bf16x8 __attribute__((ext_vector_type(8)));
typedef short bf16x4 __attribute__((ext_vector_type(4)));
typedef float f32x4  __attribute__((ext_vector_type(4)));
typedef float f32x16 __attribute__((ext_vector_type(16)));

#define D_DIM 64
#define SEQ 2048
#define BHD (SEQ * D_DIM)
#define SCALE_L2E 0.1803368801111204f   // (1/8) * log2(e)

__device__ __forceinline__ unsigned short f2bf(float f) {
    unsigned u = __builtin_bit_cast(unsigned, f);
    u += 0x7fffu + ((u >> 16) & 1u);
    return (unsigned short)(u >> 16);
}

// XOR-swizzle for row-major [R][64] bf16 tiles (row stride 128B) — T2
__device__ __forceinline__ unsigned swz(unsigned row, unsigned colByte) {
    return (row * 128u + colByte) ^ ((row & 7u) << 4);
}

__device__ __forceinline__ void gl_lds(const unsigned short* g, unsigned char* lds_generic,
                                       unsigned lds_off) {
    __builtin_amdgcn_global_load_lds(
        (const __attribute__((address_space(1))) void*)g,
        (__attribute__((address_space(3))) void*)(lds_generic + lds_off), 16, 0, 0);
}

__device__ __forceinline__ float fexp2(float x) {
    float r; asm("v_exp_f32 %0, %1" : "=v"(r) : "v"(x)); return r;
}
__device__ __forceinline__ unsigned cvtpk(float lo, float hi) {
    unsigned r; asm("v_cvt_pk_bf16_f32 %0, %1, %2" : "=v"(r) : "v"(lo), "v"(hi)); return r;
}

// ---------------- prepass 1: fp32 -> bf16 (K) ----------------
__global__ __launch_bounds__(256) void conv_bf16_kernel(const float* __restrict__ in,
                                                        unsigned short* __restrict__ out,
                                                        int n8) {
    int idx = blockIdx.x * 256 + threadIdx.x;
    for (int i = idx; i < n8; i += gridDim.x * 256) {
        const float* p = in + (size_t)i * 8;
        float4 a = *(const float4*)p;
        float4 b = *(const float4*)(p + 4);
        bf16x8 v;
        v[0] = (short)f2bf(a.x); v[1] = (short)f2bf(a.y);
        v[2] = (short)f2bf(a.z); v[3] = (short)f2bf(a.w);
        v[4] = (short)f2bf(b.x); v[5] = (short)f2bf(b.y);
        v[6] = (short)f2bf(b.z); v[7] = (short)f2bf(b.w);
        *(bf16x8*)(out + (size_t)i * 8) = v;
    }
}

// ---------------- prepass 2: V [bh][s][d] -> Vt [bh][d][s] bf16 ----------------
__global__ __launch_bounds__(256) void vt_kernel(const float* __restrict__ V,
                                                 unsigned short* __restrict__ Vt) {
    __shared__ unsigned short t[64][66];
    const int st = blockIdx.x;
    const int bh = blockIdx.y;
    const int tid = threadIdx.x;
    const float* vb = V + (size_t)bh * BHD + st * 64 * D_DIM;

    #pragma unroll
    for (int j = 0; j < 4; ++j) {
        int n = tid + 256 * j;
        int r = n >> 4;
        int c = (n & 15) << 2;
        float4 v = *(const float4*)(vb + r * D_DIM + c);
        t[r][c + 0] = f2bf(v.x); t[r][c + 1] = f2bf(v.y);
        t[r][c + 2] = f2bf(v.z); t[r][c + 3] = f2bf(v.w);
    }
    __syncthreads();
    #pragma unroll
    for (int j = 0; j < 2; ++j) {
        int m = tid + 256 * j;
        int d = m >> 3;
        int s8 = (m & 7) << 3;
        bf16x8 o;
        #pragma unroll
        for (int e = 0; e < 8; ++e) o[e] = (short)t[s8 + e][d];
        *(bf16x8*)(Vt + (size_t)bh * BHD + (size_t)d * SEQ + st * 64 + s8) = o;
    }
}

// ---------------- main: swapped-QK^T 32x32 flash attention ----------------
// 512 thr = 8 waves. Waves 0-3: q-tile i (128 rows, 32/wave); waves 4-7: q-tile 15-i.
// Per lane: one q row (col = lane&31 of wave's 32), full in-register softmax.
__global__ __launch_bounds__(512, 2) void attn_fwd(const float* __restrict__ Qp,
                                                   const unsigned short* __restrict__ Kb,
                                                   const unsigned short* __restrict__ Vtb,
                                                   float* __restrict__ Op) {
    __shared__ __align__(16) unsigned char lds[49152];  // 3 bufs x (K 8KB | Vt 8KB)

    int id = blockIdx.y * gridDim.x + blockIdx.x;   // grid (8,32)
    int wid = (id & 7) * 32 + (id >> 3);            // XCD: 4 consecutive bh per XCD
    const int i  = wid & 7;                         // pair (i, 15-i) -> constant work
    const int bh = wid >> 3;

    const int tid  = threadIdx.x;
    const int w    = tid >> 6;
    const int lane = tid & 63;
    const int l31  = lane & 31;
    const int hi2  = lane >> 5;
    const int wsub = w & 3;
    const int qt   = (w >> 2) ? (15 - i) : i;
    const int qlo  = qt * 128 + wsub * 32;          // wave's first q row
    const int t_w  = qlo >> 6;                      // last active kv-step (diagonal)
    const int TB   = 32 - 2 * i;                    // block loop length (group-B limit)

    const size_t base = (size_t)bh * BHD;
    const float* qp = Qp + base;
    const unsigned short* kb = Kb + base;
    const unsigned short* vt = Vtb + base;
    float* op = Op + base;

    // staging geometry: linear LDS byte L = tid*16; inverse-swizzled global source
    const int srow = tid >> 3;                          // row 0..63
    const int scb  = ((tid & 7) << 4) ^ ((srow & 7) << 4);
    const int kOff = srow * D_DIM + (scb >> 1);
    const int vOff = srow * SEQ + (scb >> 1);
    const unsigned sdst = (unsigned)w * 1024u;

    auto STAGE = [&](int buf, int t) {
        unsigned bb = (unsigned)buf * 16384u;
        gl_lds(kb + (size_t)t * 4096 + kOff, lds, bb + sdst);
        gl_lds(vt + (size_t)t * 64 + vOff, lds, bb + 8192u + sdst);
    };

    // Q loads first (so loop vmcnt counts only stages), then prefetch 2 tiles
    const float* qsrc = qp + (size_t)(qlo + l31) * D_DIM + hi2 * 8;
    float4 qraw[8];
    #pragma unroll
    for (int dk = 0; dk < 4; ++dk) {
        qraw[2 * dk]     = *(const float4*)(qsrc + dk * 16);
        qraw[2 * dk + 1] = *(const float4*)(qsrc + dk * 16 + 4);
    }
    STAGE(0, 0);
    STAGE(1, 1);   // TB >= 18 always

    // Q B-frags: col=q(lane-local row), k = dk*16 + hi2*8 + j ; scale folded (exp2 domain)
    bf16x8 qB[4];
    #pragma unroll
    for (int dk = 0; dk < 4; ++dk) {
        float4 a = qraw[2 * dk], b = qraw[2 * dk + 1];
        bf16x8 v;
        v[0] = (short)f2bf(a.x * SCALE_L2E); v[1] = (short)f2bf(a.y * SCALE_L2E);
        v[2] = (short)f2bf(a.z * SCALE_L2E); v[3] = (short)f2bf(a.w * SCALE_L2E);
        v[4] = (short)f2bf(b.x * SCALE_L2E); v[5] = (short)f2bf(b.y * SCALE_L2E);
        v[6] = (short)f2bf(b.z * SCALE_L2E); v[7] = (short)f2bf(b.w * SCALE_L2E);
        qB[dk] = v;
    }

    f32x16 acc[2]; acc[0] = {}; acc[1] = {};   // O^T: lane holds q=own row, 16 d each tile
    float m_r = -3.0e38f, l_r = 0.f;
    const int qg = qlo + l31;

    #pragma unroll 1
    for (int t = 0; t < TB; ++t) {
        if (t < TB - 1) asm volatile("s_waitcnt vmcnt(2)" ::: "memory");
        else            asm volatile("s_waitcnt vmcnt(0)" ::: "memory");
        __builtin_amdgcn_s_barrier();
        __builtin_amdgcn_sched_barrier(0);
        if (t + 2 < TB) STAGE((t + 2) % 3, t + 2);

        if (t <= t_w) {   // wave-uniform: beyond causal limit -> barrier-only
            const unsigned kbuf = (unsigned)(t % 3) * 16384u;
            const unsigned vbuf = kbuf + 8192u;

            // ---- swapped QK^T: St[kv][q], A=K rows kv, B=Q cols q ----
            f32x16 st[2]; st[0] = {}; st[1] = {};
            #pragma unroll
            for (int b2 = 0; b2 < 2; ++b2)
                #pragma unroll
                for (int dk = 0; dk < 4; ++dk) {
                    bf16x8 kf = *(const bf16x8*)&lds[kbuf +
                        swz((unsigned)(b2 * 32 + l31), (unsigned)(dk * 32 + hi2 * 16))];
                    st[b2] = __builtin_amdgcn_mfma_f32_32x32x16_bf16(kf, qB[dk], st[b2], 0, 0, 0);
                }

            // ---- causal mask (diagonal step only) ----
            if (t == t_w) {
                #pragma unroll
                for (int b2 = 0; b2 < 2; ++b2)
                    #pragma unroll
                    for (int r = 0; r < 16; ++r) {
                        int kvg = t * 64 + b2 * 32 + (r & 3) + 8 * (r >> 2) + 4 * hi2;
                        if (kvg > qg) st[b2][r] = -3.0e38f;
                    }
            }

            // ---- in-register online softmax (exp2 domain), 1 cross-lane op each ----
            float mx = -3.0e38f;
            #pragma unroll
            for (int b2 = 0; b2 < 2; ++b2)
                #pragma unroll
                for (int r = 0; r < 16; ++r) mx = fmaxf(mx, st[b2][r]);
            mx = fmaxf(mx, __shfl_xor(mx, 32));
            float mn = fmaxf(m_r, mx);
            float sc = fexp2(m_r - mn);
            m_r = mn;
            float p[32]; float rs = 0.f;
            #pragma unroll
            for (int b2 = 0; b2 < 2; ++b2)
                #pragma unroll
                for (int r = 0; r < 16; ++r) {
                    float e = fexp2(st[b2][r] - mn);
                    p[b2 * 16 + r] = e; rs += e;
                }
            rs += __shfl_xor(rs, 32);
            l_r = l_r * sc + rs;
            #pragma unroll
            for (int dt = 0; dt < 2; ++dt)
                #pragma unroll
                for (int r = 0; r < 16; ++r) acc[dt][r] *= sc;

            // ---- P -> bf16 B-frags via cvt_pk + cross-half exchange (T12) ----
            // lane owns kv = 8c + 4*hi2 + {0..3} per c; frag mm needs kv = 16mm+8*hi2+{0..7}
            bf16x8 pf[4];
            #pragma unroll
            for (int b2 = 0; b2 < 2; ++b2) {
                unsigned W[4][2];
                #pragma unroll
                for (int c = 0; c < 4; ++c) {
                    W[c][0] = cvtpk(p[b2 * 16 + 4 * c + 0], p[b2 * 16 + 4 * c + 1]);
                    W[c][1] = cvtpk(p[b2 * 16 + 4 * c + 2], p[b2 * 16 + 4 * c + 3]);
                }
                #pragma unroll
                for (int m = 0; m < 2; ++m) {
                    unsigned s0 = hi2 ? W[2 * m][0] : W[2 * m + 1][0];   // send partner's need
                    unsigned s1 = hi2 ? W[2 * m][1] : W[2 * m + 1][1];
                    unsigned r0 = (unsigned)__shfl_xor((int)s0, 32);
                    unsigned r1 = (unsigned)__shfl_xor((int)s1, 32);
                    int4 fw;
                    fw.x = (int)(hi2 ? r0 : W[2 * m][0]);
                    fw.y = (int)(hi2 ? r1 : W[2 * m][1]);
                    fw.z = (int)(hi2 ? W[2 * m + 1][0] : r0);
                    fw.w = (int)(hi2 ? W[2 * m + 1][1] : r1);
                    pf[b2 * 2 + m] = __builtin_bit_cast(bf16x8, fw);
                }
            }

            // ---- PV: O^T += V^T P^T  (A=V^T rows d, B=P^T cols q) ----
            #pragma unroll
            for (int dt = 0; dt < 2; ++dt)
                #pragma unroll
                for (int mm = 0; mm < 4; ++mm) {
                    bf16x8 va = *(const bf16x8*)&lds[vbuf +
                        swz((unsigned)(dt * 32 + l31), (unsigned)(mm * 32 + hi2 * 16))];
                    acc[dt] = __builtin_amdgcn_mfma_f32_32x32x16_bf16(va, pf[mm], acc[dt], 0, 0, 0);
                }
        }
    }

    // ---- epilogue: lane writes its q row; reg r=4c+s -> d = dt*32 + 8c + 4*hi2 + s ----
    float inv = 1.f / l_r;
    #pragma unroll
    for (int dt = 0; dt < 2; ++dt)
        #pragma unroll
        for (int c = 0; c < 4; ++c) {
            float4 o;
            o.x = acc[dt][4 * c + 0] * inv;
            o.y = acc[dt][4 * c + 1] * inv;
            o.z = acc[dt][4 * c + 2] * inv;
            o.w = acc[dt][4 * c + 3] * inv;
            *(float4*)(op + (size_t)qg * D_DIM + dt * 32 + 8 * c + 4 * hi2) = o;
        }
}

// ---------------- fallback (round-1 proven) if ws too small ----------------
__global__ __launch_bounds__(256) void attn_fwd_fb(
    const float* __restrict__ Qp, const float* __restrict__ Kp,
    const float* __restrict__ Vp, float* __restrict__ Op, int S)
{
    __shared__ __align__(16) unsigned char lds_k[64 * 128];
    __shared__ __align__(16) unsigned char lds_vt[64 * 128];
    __shared__ __align__(16) unsigned char lds_p[4 * 16 * 128];

    const int qt = blockIdx.x, bh = blockIdx.y, tid = threadIdx.x;
    const int w = tid >> 6, lane = tid & 63, lo = lane & 15, hi = lane >> 4;
    const size_t base = (size_t)bh * S * D_DIM;
    const float* qp = Qp + base; const float* kp = Kp + base;
    const float* vp = Vp + base; float* op = Op + base;
    const int qw = qt * 64 + w * 16;

    bf16x8 qf[2];
    {
        const float* src = qp + (size_t)(qw + lo) * D_DIM + hi * 8;
        #pragma unroll
        for (int f = 0; f < 2; ++f) {
            float4 a = *(const float4*)(src + f * 32);
            float4 b = *(const float4*)(src + f * 32 + 4);
            bf16x8 v;
            v[0] = (short)f2bf(a.x * 0.125f); v[1] = (short)f2bf(a.y * 0.125f);
            v[2] = (short)f2bf(a.z * 0.125f); v[3] = (short)f2bf(a.w * 0.125f);
            v[4] = (short)f2bf(b.x * 0.125f); v[5] = (short)f2bf(b.y * 0.125f);
            v[6] = (short)f2bf(b.z * 0.125f); v[7] = (short)f2bf(b.w * 0.125f);
            qf[f] = v;
        }
    }
    f32x4 o_acc[4]; float m_r[4], l_r[4];
    #pragma unroll
    for (int r = 0; r < 4; ++r) { m_r[r] = -__builtin_inff(); l_r[r] = 0.f; }
    #pragma unroll
    for (int dt = 0; dt < 4; ++dt) o_acc[dt] = (f32x4){0.f, 0.f, 0.f, 0.f};
    const unsigned pbase = (unsigned)w * 2048u;

    for (int t = 0; t <= qt; ++t) {
        const size_t kv0 = (size_t)t * 64;
        __syncthreads();
        #pragma unroll
        for (int j = 0; j < 4; ++j) {
            int n = tid + 256 * j;
            int r = n >> 4, c = (n & 15) << 2;
            float4 kk = *(const float4*)(kp + (kv0 + r) * D_DIM + c);
            bf16x4 kbv;
            kbv[0] = (short)f2bf(kk.x); kbv[1] = (short)f2bf(kk.y);
            kbv[2] = (short)f2bf(kk.z); kbv[3] = (short)f2bf(kk.w);
            *(bf16x4*)&lds_k[swz((unsigned)r, (unsigned)c * 2)] = kbv;
            float4 vv = *(const float4*)(vp + (kv0 + r) * D_DIM + c);
            *(unsigned short*)&lds_vt[swz((unsigned)(c + 0), (unsigned)r * 2)] = f2bf(vv.x);
            *(unsigned short*)&lds_vt[swz((unsigned)(c + 1), (unsigned)r * 2)] = f2bf(vv.y);
            *(unsigned short*)&lds_vt[swz((unsigned)(c + 2), (unsigned)r * 2)] = f2bf(vv.z);
            *(unsigned short*)&lds_vt[swz((unsigned)(c + 3), (unsigned)r * 2)] = f2bf(vv.w);
        }
        __syncthreads();

        float sc[4][4];
        #pragma unroll
        for (int kc = 0; kc < 4; ++kc) {
            f32x4 s = (f32x4){0.f, 0.f, 0.f, 0.f};
            #pragma unroll
            for (int f = 0; f < 2; ++f) {
                bf16x8 kf = *(const bf16x8*)&lds_k[swz((unsigned)(kc * 16 + lo),
                                                       (unsigned)(hi * 16 + f * 64))];
                s = __builtin_amdgcn_mfma_f32_16x16x32_bf16(qf[f], kf, s, 0, 0, 0);
            }
            #pragma unroll
            for (int r = 0; r < 4; ++r) sc[kc][r] = s[r];
        }
        if (t == qt) {
            #pragma unroll
            for (int kc = 0; kc < 4; ++kc)
                #pragma unroll
                for (int r = 0; r < 4; ++r) {
                    int qg2 = w * 16 + hi * 4 + r, kg = kc * 16 + lo;
                    if (kg > qg2) sc[kc][r] = -__builtin_inff();
                }
        }
        float scale[4];
        #pragma unroll
        for (int r = 0; r < 4; ++r) {
            float mx = fmaxf(fmaxf(sc[0][r], sc[1][r]), fmaxf(sc[2][r], sc[3][r]));
            mx = fmaxf(mx, __shfl_xor(mx, 1)); mx = fmaxf(mx, __shfl_xor(mx, 2));
            mx = fmaxf(mx, __shfl_xor(mx, 4)); mx = fmaxf(mx, __shfl_xor(mx, 8));
            float mn = fmaxf(m_r[r], mx);
            scale[r] = __expf(m_r[r] - mn); m_r[r] = mn;
            float s0 = 0.f;
            #pragma unroll
            for (int kc = 0; kc < 4; ++kc) {
                float pv = __expf(sc[kc][r] - mn); sc[kc][r] = pv; s0 += pv;
            }
            s0 += __shfl_xor(s0, 1); s0 += __shfl_xor(s0, 2);
            s0 += __shfl_xor(s0, 4); s0 += __shfl_xor(s0, 8);
            l_r[r] = l_r[r] * scale[r] + s0;
        }
        #pragma unroll
        for (int r = 0; r < 4; ++r) {
            unsigned qr = (unsigned)(hi * 4 + r);
            #pragma unroll
            for (int kc = 0; kc < 4; ++kc)
                *(unsigned short*)&lds_p[pbase + swz(qr, (unsigned)((kc * 16 + lo) * 2))] =
                    f2bf(sc[kc][r]);
            #pragma unroll
            for (int dt = 0; dt < 4; ++dt) o_acc[dt][r] *= scale[r];
        }
        bf16x8 pa0 = *(const bf16x8*)&lds_p[pbase + swz((unsigned)lo, (unsigned)(hi * 16))];
        bf16x8 pa1 = *(const bf16x8*)&lds_p[pbase + swz((unsigned)lo, (unsigned)(hi * 16 + 64))];
        #pragma unroll
        for (int dt = 0; dt < 4; ++dt) {
            bf16x8 vb0 = *(const bf16x8*)&lds_vt[swz((unsigned)(dt * 16 + lo), (unsigned)(hi * 16))];
            bf16x8 vb1 = *(const bf16x8*)&lds_vt[swz((unsigned)(dt * 16 + lo), (unsigned)(hi * 16 + 64))];
            o_acc[dt] = __builtin_amdgcn_mfma_f32_16x16x32_bf16(pa0, vb0, o_acc[dt], 0, 0, 0);
            o_acc[dt] = __builtin_amdgcn_mfma_f32_16x16x32_bf16(pa1, vb1, o_acc[dt], 0, 0, 0);
        }
    }
    const int qrow = qw + hi * 4;
    #pragma unroll
    for (int r = 0; r < 4; ++r) {
        float inv = 1.f / l_r[r];
        #pragma unroll
        for (int dt = 0; dt < 4; ++dt)
            op[(size_t)(qrow + r) * D_DIM + dt * 16 + lo] = o_acc[dt][r] * inv;
    }
}

extern "C" void kernel_launch(void* const* d_in, const int* in_sizes, int n_in,
                              void* d_out, int out_size, void* d_ws, size_t ws_size,
                              hipStream_t stream) {
    const float* q = (const float*)d_in[0];
    const float* k = (const float*)d_in[1];
    const float* v = (const float*)d_in[2];
    float* o = (float*)d_out;

    const size_t nelem = (size_t)32 * BHD;                    // 4,194,304 per tensor
    const size_t need = 2 * nelem * sizeof(unsigned short);   // 16 MiB

    if (ws_size >= need) {
        unsigned short* kbf = (unsigned short*)d_ws;
        unsigned short* vtb = kbf + nelem;
        conv_bf16_kernel<<<2048, 256, 0, stream>>>(k, kbf, (int)(nelem / 8));
        vt_kernel<<<dim3(32, 32), 256, 0, stream>>>(v, vtb);
        attn_fwd<<<dim3(8, 32), 512, 0, stream>>>(q, kbf, vtb, o);
    } else {
        attn_fwd_fb<<<dim3(32, 32), 256, 0, stream>>>(q, k, v, o, SEQ);
    }
}